// Round 1
// baseline (404.021 us; speedup 1.0000x reference)
//
#include <hip/hip_runtime.h>
#include <math.h>

#define Bn 32
#define Pn 32768
#define On 32

// d_ws layout:
// [0,    4096)  int   bpi[Bn*On]        best prior idx per (b,o)
// [4096, 4224)  int   num_pos[Bn]
// [4224, 4228)  float loss_l_total
// [4228, 4232)  float ce_total          (pos CE + mined neg CE)
// [4232, 4236)  int   np_total
// [8192, 8192+4*Bn*Pn) float ce_mine[Bn*Pn]

__device__ __forceinline__ float block_reduce_sum(float v, float* sm) {
    __syncthreads();            // safe reuse of sm across consecutive calls
#pragma unroll
    for (int off = 32; off > 0; off >>= 1) v += __shfl_down(v, off, 64);
    int lane = threadIdx.x & 63, wv = threadIdx.x >> 6;
    if (lane == 0) sm[wv] = v;
    __syncthreads();
    float s = 0.f;
    if (threadIdx.x == 0) {
        int nw = (int)(blockDim.x >> 6);
        for (int w = 0; w < nw; w++) s += sm[w];
    }
    return s;                   // valid on thread 0 only
}

// ---------------- Phase A: per-(b,o) argmax_p IoU ----------------
__global__ __launch_bounds__(256) void matchA(const float* __restrict__ priors,
                                              const float* __restrict__ targets,
                                              int* __restrict__ bpi) {
    int bo = blockIdx.x;                 // b*On + o
    const float* t = targets + (size_t)bo * 5;
    float tx1 = t[0], ty1 = t[1], tx2 = t[2], ty2 = t[3];
    float area_a = (tx2 - tx1) * (ty2 - ty1);

    float best = -1.0f; int bidx = 0;
    for (int p = threadIdx.x; p < Pn; p += blockDim.x) {
        float4 pr = ((const float4*)priors)[p];
        float px1 = pr.x - pr.z * 0.5f, py1 = pr.y - pr.w * 0.5f;
        float px2 = pr.x + pr.z * 0.5f, py2 = pr.y + pr.w * 0.5f;
        float ix1 = fmaxf(tx1, px1), iy1 = fmaxf(ty1, py1);
        float ix2 = fminf(tx2, px2), iy2 = fminf(ty2, py2);
        float iw = fmaxf(ix2 - ix1, 0.f), ih = fmaxf(iy2 - iy1, 0.f);
        float inter = iw * ih;
        float area_b = (px2 - px1) * (py2 - py1);
        float iou = inter / (area_a + area_b - inter);
        if (iou > best) { best = iou; bidx = p; }   // strict > keeps lowest p (first max)
    }
    __shared__ float sv[256];
    __shared__ int   si[256];
    sv[threadIdx.x] = best; si[threadIdx.x] = bidx;
    __syncthreads();
    for (int s = 128; s > 0; s >>= 1) {
        if ((int)threadIdx.x < s) {
            float ov = sv[threadIdx.x + s]; int oi = si[threadIdx.x + s];
            float mv = sv[threadIdx.x];     int mi = si[threadIdx.x];
            if (ov > mv || (ov == mv && oi < mi)) { sv[threadIdx.x] = ov; si[threadIdx.x] = oi; }
        }
        __syncthreads();
    }
    if (threadIdx.x == 0) bpi[bo] = si[0];
}

// ------- Phase B: per-prior matching, loc loss, CE, ce_mine -------
__global__ __launch_bounds__(256) void matchB(const float* __restrict__ loc,
                                              const float* __restrict__ conf_data,
                                              const float* __restrict__ priors,
                                              const float* __restrict__ targets,
                                              const int* __restrict__ bpi,
                                              float* __restrict__ ce_mine,
                                              int* __restrict__ num_pos,
                                              float* __restrict__ loss_l_t,
                                              float* __restrict__ ce_t,
                                              int* __restrict__ np_tot) {
    int b = blockIdx.y;
    int p = blockIdx.x * blockDim.x + threadIdx.x;

    __shared__ float tr[On][5];
    __shared__ int   sb[On];
    __shared__ float sred[4];
    if (threadIdx.x < On * 5) ((float*)tr)[threadIdx.x] = targets[(size_t)b * On * 5 + threadIdx.x];
    if (threadIdx.x < On)     sb[threadIdx.x] = bpi[b * On + threadIdx.x];
    __syncthreads();

    float4 pr = ((const float4*)priors)[p];
    float px1 = pr.x - pr.z * 0.5f, py1 = pr.y - pr.w * 0.5f;
    float px2 = pr.x + pr.z * 0.5f, py2 = pr.y + pr.w * 0.5f;
    float area_b = (px2 - px1) * (py2 - py1);

    // argmax over truths (first max wins, matching jnp.argmax axis=0)
    float best = -1.f; int bidx = 0;
#pragma unroll 4
    for (int o = 0; o < On; o++) {
        float tx1 = tr[o][0], ty1 = tr[o][1], tx2 = tr[o][2], ty2 = tr[o][3];
        float ix1 = fmaxf(tx1, px1), iy1 = fmaxf(ty1, py1);
        float ix2 = fminf(tx2, px2), iy2 = fminf(ty2, py2);
        float iw = fmaxf(ix2 - ix1, 0.f), ih = fmaxf(iy2 - iy1, 0.f);
        float inter = iw * ih;
        float area_a = (tx2 - tx1) * (ty2 - ty1);
        float iou = inter / (area_a + area_b - inter);
        if (iou > best) { best = iou; bidx = o; }
    }

    // scatter override: numpy fancy assignment, last write wins -> ascending loop
    float over = best;
    for (int o = 0; o < On; o++) {
        if (sb[o] == p) { over = 2.0f; bidx = o; }
    }

    int conf = (int)tr[bidx][4];          // labels (all 1.0 here, but read anyway)
    if (over < 0.5f) conf = 0;
    bool pos = conf > 0;

    float ll = 0.f;
    if (pos) {
        float x1 = tr[bidx][0], y1 = tr[bidx][1], x2 = tr[bidx][2], y2 = tr[bidx][3];
        float g0 = ((x1 + x2) * 0.5f - pr.x) / (0.1f * pr.z);
        float g1 = ((y1 + y2) * 0.5f - pr.y) / (0.1f * pr.w);
        float g2 = logf((x2 - x1) / pr.z) / 0.2f;
        float g3 = logf((y2 - y1) / pr.w) / 0.2f;
        const float* lp = loc + ((size_t)b * Pn + p) * 3;
        float q0 = lp[0], q1 = lp[1], q2 = lp[2];
        float dd[4] = { q0 - g0, q1 - g1, q2 - g2, q2 - g3 };
#pragma unroll
        for (int i = 0; i < 4; i++) {
            float ad = fabsf(dd[i]);
            ll += (ad < 1.f) ? 0.5f * dd[i] * dd[i] : (ad - 0.5f);
        }
    }

    const float* cp = conf_data + ((size_t)b * Pn + p) * 2;
    float c0 = cp[0], c1 = cp[1];
    float m = fmaxf(c0, c1);
    float lse = m + logf(expf(c0 - m) + expf(c1 - m));
    float picked = (conf == 1) ? c1 : c0;
    float ce = lse - picked;              // >= 0

    float pce, cem;
    if (pos) { pce = ce;  cem = 0.f; }
    else     { pce = 0.f; cem = fmaxf(ce, 0.f); }
    ce_mine[(size_t)b * Pn + p] = cem;

    float llr = block_reduce_sum(ll, sred);
    float pcer = block_reduce_sum(pce, sred);
    float cntr = block_reduce_sum(pos ? 1.f : 0.f, sred);
    if (threadIdx.x == 0) {
        if (llr != 0.f)  atomicAdd(loss_l_t, llr);
        if (pcer != 0.f) atomicAdd(ce_t, pcer);
        int c = (int)cntr;
        if (c) { atomicAdd(&num_pos[b], c); atomicAdd(np_tot, c); }
    }
}

// ---- Phase C: per-batch exact top-k sum via 8-bit radix select ----
__global__ __launch_bounds__(256) void topk(const float* __restrict__ ce_mine,
                                            const int* __restrict__ num_pos,
                                            float* __restrict__ ce_t) {
    int b = blockIdx.x;
    const float* v = ce_mine + (size_t)b * Pn;
    int k = 3 * num_pos[b];
    if (k > Pn - 1) k = Pn - 1;
    if (k <= 0) return;

    __shared__ int hist[256];
    __shared__ int s_bin, s_kk;
    __shared__ float sred[4];

    unsigned prefix = 0;
    int kk = k;
#pragma unroll
    for (int r = 0; r < 4; r++) {
        int shift = 24 - 8 * r;
        unsigned hmask = (r == 0) ? 0u : (0xFFFFFFFFu << (shift + 8));
        for (int i = threadIdx.x; i < 256; i += blockDim.x) hist[i] = 0;
        __syncthreads();
        for (int p = threadIdx.x; p < Pn; p += blockDim.x) {
            unsigned key = __float_as_uint(v[p]);   // all values >= 0: bits order-preserving
            if ((key & hmask) == prefix) atomicAdd(&hist[(key >> shift) & 255], 1);
        }
        __syncthreads();
        if (threadIdx.x == 0) {
            int c = 0, bin;
            for (bin = 255; bin >= 0; bin--) { c += hist[bin]; if (c >= kk) break; }
            if (bin < 0) bin = 0;                   // safety (shouldn't happen)
            s_bin = bin;
            s_kk = kk - (c - hist[bin]);            // rank within chosen bin
        }
        __syncthreads();
        prefix |= ((unsigned)s_bin) << shift;
        kk = s_kk;
    }

    unsigned tau = prefix;
    float tauv = __uint_as_float(tau);
    float sum = 0.f;
    for (int p = threadIdx.x; p < Pn; p += blockDim.x) {
        float val = v[p];
        if (__float_as_uint(val) > tau) sum += val;
    }
    float tot = block_reduce_sum(sum, sred);
    if (threadIdx.x == 0) {
        // count(> tau) = k - kk; ties at tau contribute kk * tau (exact, tie-agnostic)
        atomicAdd(ce_t, tot + (float)kk * tauv);
    }
}

// ---------------- Phase D: finalize ----------------
__global__ void finalize(const float* __restrict__ loss_l_t,
                         const float* __restrict__ ce_t,
                         const int* __restrict__ np_tot,
                         float* __restrict__ out) {
    float N = (float)(*np_tot);
    out[0] = *loss_l_t / N;
    out[1] = *ce_t / N;
}

extern "C" void kernel_launch(void* const* d_in, const int* in_sizes, int n_in,
                              void* d_out, int out_size, void* d_ws, size_t ws_size,
                              hipStream_t stream) {
    const float* loc     = (const float*)d_in[0];  // (B,P,3)
    const float* conf    = (const float*)d_in[1];  // (B,P,2)
    const float* priors  = (const float*)d_in[2];  // (P,4)
    const float* targets = (const float*)d_in[3];  // (B,O,5)
    float* out = (float*)d_out;

    char* ws = (char*)d_ws;
    int*   bpi      = (int*)ws;
    int*   num_pos  = (int*)(ws + 4096);
    float* loss_l_t = (float*)(ws + 4224);
    float* ce_t     = (float*)(ws + 4228);
    int*   np_tot   = (int*)(ws + 4232);
    float* ce_mine  = (float*)(ws + 8192);

    hipMemsetAsync(ws, 0, 8192, stream);

    hipLaunchKernelGGL(matchA, dim3(Bn * On), dim3(256), 0, stream, priors, targets, bpi);
    hipLaunchKernelGGL(matchB, dim3(Pn / 256, Bn), dim3(256), 0, stream,
                       loc, conf, priors, targets, bpi, ce_mine, num_pos, loss_l_t, ce_t, np_tot);
    hipLaunchKernelGGL(topk, dim3(Bn), dim3(256), 0, stream, ce_mine, num_pos, ce_t);
    hipLaunchKernelGGL(finalize, dim3(1), dim3(1), 0, stream, loss_l_t, ce_t, np_tot, out);
}

// Round 2
// 319.567 us; speedup vs baseline: 1.2643x; 1.2643x over previous
//
#include <hip/hip_runtime.h>
#include <math.h>

#define Bn 32
#define Pn 32768
#define On 32

// d_ws layout:
// [0,     8192)  u64   bpm[Bn*On]   packed (iou_bits<<32 | (Pn-1-p)) per (b,o)
// [8192,  8320)  int   num_pos[Bn]
// [8320,  8324)  float loss_l_total
// [8324,  8328)  float ce_total
// [8328,  8332)  int   np_total
// [16384, 16384+4*Bn*Pn) float ce_mine[Bn*Pn]

// ---------------- Phase A: per-(b,o) argmax_p IoU ----------------
// grid (Bn*On, 4), block 256. Each block scans 8192 priors, one packed
// u64 atomicMax per block. Cross-multiply compare: no division in the loop.
__global__ __launch_bounds__(256) void matchA(const float* __restrict__ priors,
                                              const float* __restrict__ targets,
                                              unsigned long long* __restrict__ bpm) {
    int bo = blockIdx.x;
    int chunk = blockIdx.y;
    const float* t = targets + (size_t)bo * 5;
    float tx1 = t[0], ty1 = t[1], tx2 = t[2], ty2 = t[3];
    float area_a = (tx2 - tx1) * (ty2 - ty1);

    int p = chunk * (Pn / 4) + threadIdx.x;
    float bI = 0.f, bU = 1.f; int bp = p;   // all-zero overlap -> keep first p in stride
#pragma unroll 8
    for (int i = 0; i < (Pn / 4) / 256; i++, p += 256) {
        float4 pr = ((const float4*)priors)[p];
        float px1 = pr.x - pr.z * 0.5f, py1 = pr.y - pr.w * 0.5f;
        float px2 = pr.x + pr.z * 0.5f, py2 = pr.y + pr.w * 0.5f;
        float ix1 = fmaxf(tx1, px1), iy1 = fmaxf(ty1, py1);
        float ix2 = fminf(tx2, px2), iy2 = fminf(ty2, py2);
        float iw = fmaxf(ix2 - ix1, 0.f), ih = fmaxf(iy2 - iy1, 0.f);
        float I = iw * ih;
        float U = area_a + (px2 - px1) * (py2 - py1) - I;
        if (I * bU > bI * U) { bI = I; bU = U; bp = p; }   // strict >: first max wins
    }
    // one precise division per thread so cross-thread ties use f32-rounded iou like ref
    float iou = bI / bU;
    unsigned long long key = ((unsigned long long)__float_as_uint(iou) << 32)
                           | (unsigned)(Pn - 1 - bp);     // bigger low32 = smaller p

    __shared__ unsigned long long sk[256];
    sk[threadIdx.x] = key;
    __syncthreads();
    for (int s = 128; s > 0; s >>= 1) {
        if ((int)threadIdx.x < s) {
            unsigned long long o = sk[threadIdx.x + s];
            if (o > sk[threadIdx.x]) sk[threadIdx.x] = o;
        }
        __syncthreads();
    }
    if (threadIdx.x == 0) atomicMax(&bpm[bo], sk[0]);
}

// ------- Phase B: per-prior matching, loc loss, CE, ce_mine -------
__global__ __launch_bounds__(256) void matchB(const float* __restrict__ loc,
                                              const float* __restrict__ conf_data,
                                              const float* __restrict__ priors,
                                              const float* __restrict__ targets,
                                              const unsigned long long* __restrict__ bpm,
                                              float* __restrict__ ce_mine,
                                              int* __restrict__ num_pos,
                                              float* __restrict__ loss_l_t,
                                              float* __restrict__ ce_t,
                                              int* __restrict__ np_tot) {
    int b = blockIdx.y;
    int p = blockIdx.x * blockDim.x + threadIdx.x;

    __shared__ float4 tb[On];   // x1,y1,x2,y2
    __shared__ float  ta[On];   // area
    __shared__ float  lb[On];   // label
    __shared__ int    sb[On];   // best prior idx per truth
    __shared__ float  sred[12];
    if (threadIdx.x < On) {
        int o = threadIdx.x;
        const float* t = targets + ((size_t)b * On + o) * 5;
        float x1 = t[0], y1 = t[1], x2 = t[2], y2 = t[3];
        tb[o] = make_float4(x1, y1, x2, y2);
        ta[o] = (x2 - x1) * (y2 - y1);
        lb[o] = t[4];
        sb[o] = Pn - 1 - (int)(bpm[b * On + o] & 0xFFFFFFFFull);
    }
    __syncthreads();

    float4 pr = ((const float4*)priors)[p];
    float px1 = pr.x - pr.z * 0.5f, py1 = pr.y - pr.w * 0.5f;
    float px2 = pr.x + pr.z * 0.5f, py2 = pr.y + pr.w * 0.5f;
    float area_b = (px2 - px1) * (py2 - py1);

    // argmax over truths (first max wins), division-free
    float bI = 0.f, bU = 1.f; int bidx = 0;
#pragma unroll
    for (int o = 0; o < On; o++) {
        float4 tt = tb[o];
        float ix1 = fmaxf(tt.x, px1), iy1 = fmaxf(tt.y, py1);
        float ix2 = fminf(tt.z, px2), iy2 = fminf(tt.w, py2);
        float iw = fmaxf(ix2 - ix1, 0.f), ih = fmaxf(iy2 - iy1, 0.f);
        float I = iw * ih;
        float U = ta[o] + area_b - I;
        if (I * bU > bI * U) { bI = I; bU = U; bidx = o; }
    }

    // scatter override: ascending loop, last write wins (numpy semantics)
    bool forced = false;
#pragma unroll
    for (int o = 0; o < On; o++) {
        if (sb[o] == p) { forced = true; bidx = o; }
    }

    int cf;
    if (forced)                    cf = (int)lb[bidx];
    else if (bI >= 0.5f * bU)      cf = (int)lb[bidx];   // iou >= THRESHOLD
    else                           cf = 0;
    bool pos = cf > 0;

    float ll = 0.f;
    if (pos) {
        float4 tt = tb[bidx];
        float g0 = ((tt.x + tt.z) * 0.5f - pr.x) / (0.1f * pr.z);
        float g1 = ((tt.y + tt.w) * 0.5f - pr.y) / (0.1f * pr.w);
        float g2 = __logf((tt.z - tt.x) / pr.z) * 5.0f;   // /0.2
        float g3 = __logf((tt.w - tt.y) / pr.w) * 5.0f;
        const float* lp = loc + ((size_t)b * Pn + p) * 3;
        float q0 = lp[0], q1 = lp[1], q2 = lp[2];
        float dd[4] = { q0 - g0, q1 - g1, q2 - g2, q2 - g3 };
#pragma unroll
        for (int i = 0; i < 4; i++) {
            float ad = fabsf(dd[i]);
            ll += (ad < 1.f) ? 0.5f * dd[i] * dd[i] : (ad - 0.5f);
        }
    }

    const float* cp = conf_data + ((size_t)b * Pn + p) * 2;
    float c0 = cp[0], c1 = cp[1];
    float m = fmaxf(c0, c1);
    float lse = m + __logf(__expf(c0 - m) + __expf(c1 - m));
    float ce = lse - (cf ? c1 : c0);              // >= 0

    float pce, cem;
    if (pos) { pce = ce;  cem = 0.f; }
    else     { pce = 0.f; cem = fmaxf(ce, 0.f); }
    ce_mine[(size_t)b * Pn + p] = cem;

    // fused 3-value block reduce
    float cnt = pos ? 1.f : 0.f;
#pragma unroll
    for (int off = 32; off > 0; off >>= 1) {
        ll  += __shfl_down(ll,  off, 64);
        pce += __shfl_down(pce, off, 64);
        cnt += __shfl_down(cnt, off, 64);
    }
    int lane = threadIdx.x & 63, wv = threadIdx.x >> 6;
    if (lane == 0) { sred[wv * 3] = ll; sred[wv * 3 + 1] = pce; sred[wv * 3 + 2] = cnt; }
    __syncthreads();
    if (threadIdx.x == 0) {
        float llr = 0, pcer = 0, cntr = 0;
        for (int w = 0; w < 4; w++) { llr += sred[w*3]; pcer += sred[w*3+1]; cntr += sred[w*3+2]; }
        if (llr != 0.f)  atomicAdd(loss_l_t, llr);
        if (pcer != 0.f) atomicAdd(ce_t, pcer);
        int c = (int)cntr;
        if (c) { atomicAdd(&num_pos[b], c); atomicAdd(np_tot, c); }
    }
}

// ---- Phase C: per-batch exact top-k sum via 8-bit radix select ----
// 1024 threads/block; per-wave replicated histograms to avoid LDS atomic
// serialization on the clustered exponent bins.
__global__ __launch_bounds__(1024) void topk(const float* __restrict__ ce_mine,
                                             const int* __restrict__ num_pos,
                                             float* __restrict__ ce_t) {
    int b = blockIdx.x;
    const float* v = ce_mine + (size_t)b * Pn;
    int k = 3 * num_pos[b];
    if (k > Pn - 1) k = Pn - 1;
    if (k <= 0) return;

    __shared__ int hist[16][256];    // per-wave replicated
    __shared__ int merged[256];
    __shared__ int s_bin, s_kk;
    __shared__ float sred[16];
    int wv = threadIdx.x >> 6;

    unsigned prefix = 0;
    int kk = k;
#pragma unroll
    for (int r = 0; r < 4; r++) {
        int shift = 24 - 8 * r;
        unsigned hmask = (r == 0) ? 0u : (0xFFFFFFFFu << (shift + 8));
        for (int i = threadIdx.x; i < 16 * 256; i += 1024) ((int*)hist)[i] = 0;
        __syncthreads();
        for (int p = threadIdx.x; p < Pn; p += 1024) {
            unsigned key = __float_as_uint(v[p]);   // values >= 0: bits order-preserving
            if ((key & hmask) == prefix) atomicAdd(&hist[wv][(key >> shift) & 255], 1);
        }
        __syncthreads();
        if (threadIdx.x < 256) {
            int s = 0;
#pragma unroll
            for (int w = 0; w < 16; w++) s += hist[w][threadIdx.x];
            merged[threadIdx.x] = s;
        }
        __syncthreads();
        if (threadIdx.x == 0) {
            int c = 0, bin;
            for (bin = 255; bin >= 0; bin--) { c += merged[bin]; if (c >= kk) break; }
            if (bin < 0) bin = 0;
            s_bin = bin;
            s_kk = kk - (c - merged[bin]);
        }
        __syncthreads();
        prefix |= ((unsigned)s_bin) << shift;
        kk = s_kk;
    }

    unsigned tau = prefix;
    float tauv = __uint_as_float(tau);
    float sum = 0.f;
    for (int p = threadIdx.x; p < Pn; p += 1024) {
        float val = v[p];
        if (__float_as_uint(val) > tau) sum += val;
    }
#pragma unroll
    for (int off = 32; off > 0; off >>= 1) sum += __shfl_down(sum, off, 64);
    if ((threadIdx.x & 63) == 0) sred[wv] = sum;
    __syncthreads();
    if (threadIdx.x == 0) {
        float tot = 0.f;
        for (int w = 0; w < 16; w++) tot += sred[w];
        // ties at tau contribute kk * tau (tie-agnostic, exact)
        atomicAdd(ce_t, tot + (float)kk * tauv);
    }
}

// ---------------- Phase D: finalize ----------------
__global__ void finalize(const float* __restrict__ loss_l_t,
                         const float* __restrict__ ce_t,
                         const int* __restrict__ np_tot,
                         float* __restrict__ out) {
    float N = (float)(*np_tot);
    out[0] = *loss_l_t / N;
    out[1] = *ce_t / N;
}

extern "C" void kernel_launch(void* const* d_in, const int* in_sizes, int n_in,
                              void* d_out, int out_size, void* d_ws, size_t ws_size,
                              hipStream_t stream) {
    const float* loc     = (const float*)d_in[0];  // (B,P,3)
    const float* conf    = (const float*)d_in[1];  // (B,P,2)
    const float* priors  = (const float*)d_in[2];  // (P,4)
    const float* targets = (const float*)d_in[3];  // (B,O,5)
    float* out = (float*)d_out;

    char* ws = (char*)d_ws;
    unsigned long long* bpm = (unsigned long long*)ws;
    int*   num_pos  = (int*)(ws + 8192);
    float* loss_l_t = (float*)(ws + 8320);
    float* ce_t     = (float*)(ws + 8324);
    int*   np_tot   = (int*)(ws + 8328);
    float* ce_mine  = (float*)(ws + 16384);

    hipMemsetAsync(ws, 0, 16384, stream);

    hipLaunchKernelGGL(matchA, dim3(Bn * On, 4), dim3(256), 0, stream, priors, targets, bpm);
    hipLaunchKernelGGL(matchB, dim3(Pn / 256, Bn), dim3(256), 0, stream,
                       loc, conf, priors, targets, bpm, ce_mine, num_pos, loss_l_t, ce_t, np_tot);
    hipLaunchKernelGGL(topk, dim3(Bn), dim3(1024), 0, stream, ce_mine, num_pos, ce_t);
    hipLaunchKernelGGL(finalize, dim3(1), dim3(1), 0, stream, loss_l_t, ce_t, np_tot, out);
}

// Round 3
// 171.686 us; speedup vs baseline: 2.3533x; 1.8613x over previous
//
#include <hip/hip_runtime.h>
#include <math.h>

#define Bn 32
#define Pn 32768
#define On 32
#define TPB 256
#define PPT 4                 // priors per thread in matchB
#define BP  (TPB * PPT)       // priors per matchB block = 1024

// d_ws layout:
// [0,     8192)  u64   bpm[Bn*On]   packed (iou_bits<<32 | (Pn-1-p)) per (b,o)
// [8192,  8320)  int   num_pos[Bn]
// [8320,  8324)  float loss_l_total
// [8324,  8328)  float ce_total
// [8328,  8332)  int   np_total
// [16384, 16384+4*Bn*Pn) float ce_mine[Bn*Pn]

// ---------------- Phase A: per-(b,o) argmax_p IoU ----------------
// grid (Bn*On, 4), 256 threads. 4 independent compare chains per thread
// (8 candidates each) to overlap the loop-carried argmax dependency.
__global__ __launch_bounds__(256) void matchA(const float4* __restrict__ priors,
                                              const float* __restrict__ targets,
                                              unsigned long long* __restrict__ bpm) {
    int bo = blockIdx.x, chunk = blockIdx.y;
    const float* t = targets + (size_t)bo * 5;
    float tx1 = t[0], ty1 = t[1], tx2 = t[2], ty2 = t[3];
    float area_a = (tx2 - tx1) * (ty2 - ty1);

    int base = chunk * (Pn / 4) + threadIdx.x;
    float bI[4] = {0.f, 0.f, 0.f, 0.f};
    float bU[4] = {1.f, 1.f, 1.f, 1.f};
    int   bp[4];
#pragma unroll
    for (int c = 0; c < 4; c++) bp[c] = base + 256 * c;

#pragma unroll 2
    for (int i = 0; i < 8; i++) {
#pragma unroll
        for (int c = 0; c < 4; c++) {
            int p = base + (i * 4 + c) * 256;       // ascending in i per chain
            float4 pr = priors[p];
            float px1 = pr.x - pr.z * 0.5f, py1 = pr.y - pr.w * 0.5f;
            float px2 = pr.x + pr.z * 0.5f, py2 = pr.y + pr.w * 0.5f;
            float ix1 = fmaxf(tx1, px1), iy1 = fmaxf(ty1, py1);
            float ix2 = fminf(tx2, px2), iy2 = fminf(ty2, py2);
            float iw = fmaxf(ix2 - ix1, 0.f), ih = fmaxf(iy2 - iy1, 0.f);
            float I = iw * ih;
            float U = area_a + (px2 - px1) * (py2 - py1) - I;
            if (I * bU[c] > bI[c] * U) { bI[c] = I; bU[c] = U; bp[c] = p; }
        }
    }
    // merge chains with f32-quotient keys (ties -> smaller p via low32)
    unsigned long long key = 0ull;
#pragma unroll
    for (int c = 0; c < 4; c++) {
        float iou = bI[c] / bU[c];
        unsigned long long kc = ((unsigned long long)__float_as_uint(iou) << 32)
                              | (unsigned)(Pn - 1 - bp[c]);
        if (kc > key) key = kc;
    }

    __shared__ unsigned long long sk[256];
    sk[threadIdx.x] = key;
    __syncthreads();
    for (int s = 128; s > 0; s >>= 1) {
        if ((int)threadIdx.x < s) {
            unsigned long long o = sk[threadIdx.x + s];
            if (o > sk[threadIdx.x]) sk[threadIdx.x] = o;
        }
        __syncthreads();
    }
    if (threadIdx.x == 0) atomicMax(&bpm[bo], sk[0]);
}

// ------- Phase B: per-prior matching, loc loss, CE, ce_mine -------
// grid (Pn/BP, Bn), 256 threads, 4 priors/thread (strided by 256).
__global__ __launch_bounds__(256) void matchB(const float* __restrict__ loc,
                                              const float2* __restrict__ conf2,
                                              const float4* __restrict__ priors,
                                              const float* __restrict__ targets,
                                              const unsigned long long* __restrict__ bpm,
                                              float* __restrict__ ce_mine,
                                              int* __restrict__ num_pos,
                                              float* __restrict__ loss_l_t,
                                              float* __restrict__ ce_t,
                                              int* __restrict__ np_tot) {
    int b = blockIdx.y;
    int base = blockIdx.x * BP;
    int tid = threadIdx.x;

    __shared__ float4 tb[On];
    __shared__ float  ta[On], lb[On];
    __shared__ int    forced[BP];    // truth index forcing this prior, else -1
    __shared__ float  sred[12];

#pragma unroll
    for (int j = 0; j < PPT; j++) forced[tid + 256 * j] = -1;
    int sp = -1;
    if (tid < On) {
        const float* t = targets + ((size_t)b * On + tid) * 5;
        float x1 = t[0], y1 = t[1], x2 = t[2], y2 = t[3];
        tb[tid] = make_float4(x1, y1, x2, y2);
        ta[tid] = (x2 - x1) * (y2 - y1);
        lb[tid] = t[4];
        sp = Pn - 1 - (int)(bpm[b * On + tid] & 0xFFFFFFFFull);
    }
    __syncthreads();            // forced[] init complete
    if (tid < On && sp >= base && sp < base + BP)
        atomicMax(&forced[sp - base], tid);   // duplicate bpi: max o == numpy last-write
    __syncthreads();

    float px1[PPT], py1[PPT], px2[PPT], py2[PPT], ab[PPT], pcx[PPT], pcy[PPT], pw[PPT], ph[PPT];
#pragma unroll
    for (int j = 0; j < PPT; j++) {
        float4 pr = priors[base + tid + 256 * j];
        pcx[j] = pr.x; pcy[j] = pr.y; pw[j] = pr.z; ph[j] = pr.w;
        px1[j] = pr.x - pr.z * 0.5f; py1[j] = pr.y - pr.w * 0.5f;
        px2[j] = pr.x + pr.z * 0.5f; py2[j] = pr.y + pr.w * 0.5f;
        ab[j]  = (px2[j] - px1[j]) * (py2[j] - py1[j]);
    }

    float bI[PPT] = {0.f, 0.f, 0.f, 0.f};
    float bU[PPT] = {1.f, 1.f, 1.f, 1.f};
    int   bx[PPT] = {0, 0, 0, 0};
#pragma unroll 4
    for (int o = 0; o < On; o++) {
        float4 tt = tb[o];
        float  a  = ta[o];
#pragma unroll
        for (int j = 0; j < PPT; j++) {
            float ix1 = fmaxf(tt.x, px1[j]), iy1 = fmaxf(tt.y, py1[j]);
            float ix2 = fminf(tt.z, px2[j]), iy2 = fminf(tt.w, py2[j]);
            float iw = fmaxf(ix2 - ix1, 0.f), ih = fmaxf(iy2 - iy1, 0.f);
            float I = iw * ih;
            float U = a + ab[j] - I;
            if (I * bU[j] > bI[j] * U) { bI[j] = I; bU[j] = U; bx[j] = o; }
        }
    }

    float ll_s = 0.f, pce_s = 0.f, cnt_s = 0.f;
#pragma unroll
    for (int j = 0; j < PPT; j++) {
        int p = base + tid + 256 * j;
        int fo = forced[tid + 256 * j];
        int bidx = (fo >= 0) ? fo : bx[j];
        int cf;
        if (fo >= 0)                      cf = (int)lb[bidx];
        else if (bI[j] >= 0.5f * bU[j])   cf = (int)lb[bidx];
        else                              cf = 0;
        bool pos = cf > 0;

        if (pos) {
            float4 tt = tb[bidx];
            float g0 = ((tt.x + tt.z) * 0.5f - pcx[j]) / (0.1f * pw[j]);
            float g1 = ((tt.y + tt.w) * 0.5f - pcy[j]) / (0.1f * ph[j]);
            float g2 = __logf((tt.z - tt.x) / pw[j]) * 5.0f;
            float g3 = __logf((tt.w - tt.y) / ph[j]) * 5.0f;
            const float* lp = loc + ((size_t)b * Pn + p) * 3;
            float q0 = lp[0], q1 = lp[1], q2 = lp[2];
            float dd[4] = { q0 - g0, q1 - g1, q2 - g2, q2 - g3 };
#pragma unroll
            for (int i = 0; i < 4; i++) {
                float ad = fabsf(dd[i]);
                ll_s += (ad < 1.f) ? 0.5f * dd[i] * dd[i] : (ad - 0.5f);
            }
            cnt_s += 1.f;
        }

        float2 cc = conf2[(size_t)b * Pn + p];
        float m = fmaxf(cc.x, cc.y);
        float lse = m + __logf(__expf(cc.x - m) + __expf(cc.y - m));
        float ce = lse - (cf ? cc.y : cc.x);       // >= 0
        if (pos) { pce_s += ce; ce = 0.f; }
        ce_mine[(size_t)b * Pn + p] = fmaxf(ce, 0.f);
    }

    // fused 3-value block reduce
#pragma unroll
    for (int off = 32; off > 0; off >>= 1) {
        ll_s  += __shfl_down(ll_s,  off, 64);
        pce_s += __shfl_down(pce_s, off, 64);
        cnt_s += __shfl_down(cnt_s, off, 64);
    }
    int lane = tid & 63, wv = tid >> 6;
    if (lane == 0) { sred[wv * 3] = ll_s; sred[wv * 3 + 1] = pce_s; sred[wv * 3 + 2] = cnt_s; }
    __syncthreads();
    if (tid == 0) {
        float llr = 0, pcer = 0, cntr = 0;
        for (int w = 0; w < 4; w++) { llr += sred[w*3]; pcer += sred[w*3+1]; cntr += sred[w*3+2]; }
        if (llr != 0.f)  atomicAdd(loss_l_t, llr);
        if (pcer != 0.f) atomicAdd(ce_t, pcer);
        int c = (int)cntr;
        if (c) { atomicAdd(&num_pos[b], c); atomicAdd(np_tot, c); }
    }
}

// ---- Phase C: exact top-k sum via register-resident bisection ----
// One block per batch, 1024 threads, 32 values/thread held in VGPRs.
// ~31 rounds of count(v > mid) — no LDS atomics, no global re-reads.
__global__ __launch_bounds__(1024) void topk(const float* __restrict__ ce_mine,
                                             const int* __restrict__ num_pos,
                                             float* __restrict__ ce_t) {
    int b = blockIdx.x, tid = threadIdx.x;
    const float4* v4 = (const float4*)(ce_mine + (size_t)b * Pn);
    float4 r[8];
#pragma unroll
    for (int i = 0; i < 8; i++) r[i] = v4[i * 1024 + tid];

    int k = 3 * num_pos[b];
    if (k > Pn - 1) k = Pn - 1;
    if (k <= 0) return;                       // uniform across block

    __shared__ int   scnt[16];
    __shared__ float ssum[16];
    __shared__ int   s_tot;

    // invariant: count(> lo) >= k, count(> hi) < k  (values >= 0, finite)
    unsigned lo = 0u, hi = 0x7F800000u;
    while (hi - lo > 1u) {
        unsigned mid = lo + ((hi - lo) >> 1);
        float mf = __uint_as_float(mid);
        int c = 0;
#pragma unroll
        for (int i = 0; i < 8; i++) {
            c += (r[i].x > mf) + (r[i].y > mf) + (r[i].z > mf) + (r[i].w > mf);
        }
#pragma unroll
        for (int off = 32; off > 0; off >>= 1) c += __shfl_down(c, off, 64);
        if ((tid & 63) == 0) scnt[tid >> 6] = c;
        __syncthreads();
        if (tid == 0) { int t = 0; for (int w = 0; w < 16; w++) t += scnt[w]; s_tot = t; }
        __syncthreads();
        if (s_tot >= k) lo = mid; else hi = mid;
    }
    // tau = hi is the k-th largest value (count(>tau) < k <= count(>=tau))
    float tv = __uint_as_float(hi);
    float s = 0.f; int c = 0;
#pragma unroll
    for (int i = 0; i < 8; i++) {
        if (r[i].x > tv) { s += r[i].x; c++; }
        if (r[i].y > tv) { s += r[i].y; c++; }
        if (r[i].z > tv) { s += r[i].z; c++; }
        if (r[i].w > tv) { s += r[i].w; c++; }
    }
#pragma unroll
    for (int off = 32; off > 0; off >>= 1) {
        s += __shfl_down(s, off, 64);
        c += __shfl_down(c, off, 64);
    }
    if ((tid & 63) == 0) { ssum[tid >> 6] = s; scnt[tid >> 6] = c; }
    __syncthreads();
    if (tid == 0) {
        float st = 0.f; int ct = 0;
        for (int w = 0; w < 16; w++) { st += ssum[w]; ct += scnt[w]; }
        atomicAdd(ce_t, st + (float)(k - ct) * tv);   // ties at tau, tie-agnostic exact
    }
}

// ---------------- Phase D: finalize ----------------
__global__ void finalize(const float* __restrict__ loss_l_t,
                         const float* __restrict__ ce_t,
                         const int* __restrict__ np_tot,
                         float* __restrict__ out) {
    float N = (float)(*np_tot);
    out[0] = *loss_l_t / N;
    out[1] = *ce_t / N;
}

extern "C" void kernel_launch(void* const* d_in, const int* in_sizes, int n_in,
                              void* d_out, int out_size, void* d_ws, size_t ws_size,
                              hipStream_t stream) {
    const float* loc     = (const float*)d_in[0];  // (B,P,3)
    const float* conf    = (const float*)d_in[1];  // (B,P,2)
    const float* priors  = (const float*)d_in[2];  // (P,4)
    const float* targets = (const float*)d_in[3];  // (B,O,5)
    float* out = (float*)d_out;

    char* ws = (char*)d_ws;
    unsigned long long* bpm = (unsigned long long*)ws;
    int*   num_pos  = (int*)(ws + 8192);
    float* loss_l_t = (float*)(ws + 8320);
    float* ce_t     = (float*)(ws + 8324);
    int*   np_tot   = (int*)(ws + 8328);
    float* ce_mine  = (float*)(ws + 16384);

    hipMemsetAsync(ws, 0, 16384, stream);

    hipLaunchKernelGGL(matchA, dim3(Bn * On, 4), dim3(256), 0, stream,
                       (const float4*)priors, targets, bpm);
    hipLaunchKernelGGL(matchB, dim3(Pn / BP, Bn), dim3(256), 0, stream,
                       loc, (const float2*)conf, (const float4*)priors, targets, bpm,
                       ce_mine, num_pos, loss_l_t, ce_t, np_tot);
    hipLaunchKernelGGL(topk, dim3(Bn), dim3(1024), 0, stream, ce_mine, num_pos, ce_t);
    hipLaunchKernelGGL(finalize, dim3(1), dim3(1), 0, stream, loss_l_t, ce_t, np_tot, out);
}